// Round 9
// baseline (729.283 us; speedup 1.0000x reference)
//
#include <hip/hip_runtime.h>
#include <hip/hip_bf16.h>

#define B_ 4
#define N_ 512
#define F_ 64
#define H_ 64
#define K_ 64
#define BN_ (B_*N_)
#define EPS_ 1e-14f

__device__ __forceinline__ float lane_bcast(float v, int lane) {
    return __int_as_float(__builtin_amdgcn_readlane(__float_as_int(v), lane));
}

// ws (floats): PJ_EW[BN*64] | PI_EW[BN*64] | PJ_ES[BN*64] | PI_ES[BN*64] | PJ_SA[BN] | PI_SA[BN]
#define W_PJEW 0
#define W_PIEW (BN_*64)
#define W_PJES (2*BN_*64)
#define W_PIES (3*BN_*64)
#define W_PJSA (4*BN_*64)
#define W_PISA (4*BN_*64 + BN_)

__global__ __launch_bounds__(64) void proj_kernel(
    const float* __restrict__ h, const float* __restrict__ W_ew,
    const float* __restrict__ W_sa, const float* __restrict__ W_es,
    float* __restrict__ ws)
{
    const int node = blockIdx.x;      // b*N + n
    const int t = threadIdx.x;        // 0..63 = output channel
    __shared__ float sh[F_];
    sh[t] = h[node*F_ + t];
    __syncthreads();
    float a_jew=0.f, a_iew=0.f, a_jes=0.f, a_ies=0.f, a_jsa=0.f, a_isa=0.f;
    for (int f = 0; f < F_; ++f) {
        const float hv = sh[f];
        a_jew += hv * W_ew[f*K_ + t];          // h @ W_ew[:F]
        a_iew += hv * W_ew[(F_+f)*K_ + t];     // h @ W_ew[F:]
        a_jes += hv * W_es[(1+f)*H_ + t];      // h @ W_es[1:][:F]
        a_ies += hv * W_es[(1+F_+f)*H_ + t];   // h @ W_es[1:][F:]
        a_jsa += hv * W_sa[f];                 // h @ W_sa[:F]
        a_isa += hv * W_sa[F_+f];              // h @ W_sa[F:]
    }
    ws[W_PJEW + node*K_ + t] = a_jew;
    ws[W_PIEW + node*K_ + t] = a_iew;
    ws[W_PJES + node*H_ + t] = a_jes;
    ws[W_PIES + node*H_ + t] = a_ies;
    if (t == 0) { ws[W_PJSA + node] = a_jsa; ws[W_PISA + node] = a_isa; }
}

__global__ __launch_bounds__(64) void main_kernel(
    const float* __restrict__ h, const float* __restrict__ x,
    const float* __restrict__ b_ew, const float* __restrict__ b_es,
    const float* __restrict__ W_es, const float* __restrict__ W_c1,
    const float* __restrict__ b_c1, const float* __restrict__ W_c2,
    const float* __restrict__ b_c2, const float* __restrict__ W_n,
    const float* __restrict__ b_n,
    const float* __restrict__ ws, float* __restrict__ out)
{
    const int bi = blockIdx.x;        // b*N + i
    const int b  = bi >> 9;
    const int t  = threadIdx.x;       // 0..63 = channel (k or h index)
    const int base = b * N_;

    // reference: pair(i,j) = pj[j] + pi[i]; pj = h@W[:F], pi = h@W[F:]
    const float pi_ew_t = ws[W_PIEW + bi*K_ + t] + b_ew[t];
    const float pi_es_t = ws[W_PIES + bi*H_ + t] + b_es[t];
    const float pisa    = ws[W_PISA + bi];
    const float xi0 = x[bi*3+0], xi1 = x[bi*3+1], xi2 = x[bi*3+2];
    const float wes0_t = W_es[t];     // row 0 of W_es (weight of `filtered`)
    const float wc2_t  = W_c2[t];
    const float bc1_t  = b_c1[t];
    const float bc2    = b_c2[0];

    float wc1r[H_];
    for (int hh = 0; hh < H_; ++hh) wc1r[hh] = W_c1[hh*H_ + t];

    float att0=0.f, att1=0.f, att2=0.f, hea=0.f, sum_e=0.f;
    float xa0=0.f, xa1=0.f, xa2=0.f;   // per-lane: sum_j d_c * cp_lane
    float db0=0.f, db1=0.f, db2=0.f;   // sum_j d_c (lane-uniform)

    for (int j = 0; j < N_; ++j) {
        const int gj = base + j;
        const float d0  = x[gj*3+0] - xi0;
        const float d1  = x[gj*3+1] - xi1;
        const float d2c = x[gj*3+2] - xi2;
        const float d2s = d0*d0 + d1*d1 + d2c*d2c;
        const float nrm = sqrtf(d2s + EPS_);
        const float e   = __expf(nrm);          // softmax numerator over j
        sum_e += e;
        const float filt = 1.0f / (nrm + 0.1f);
        const float inv  = 1.0f / (nrm*nrm + EPS_);
        const float v0 = d0*inv, v1 = d1*inv, v2 = d2c*inv;

        const float ewx = ws[W_PJEW + (size_t)gj*K_ + t] + pi_ew_t;
        const float ewt = tanhf(ewx);
        att0 += ewt*v0; att1 += ewt*v1; att2 += ewt*v2;

        const float pre = filt*wes0_t + ws[W_PJES + (size_t)gj*H_ + t] + pi_es_t;
        const float he  = pre / (1.0f + __expf(-pre));   // silu

        const float sv  = ws[W_PJSA + gj] + pisa;
        const float sem = (sv >= 0.f) ? sv : 0.01f*sv;   // leaky relu
        hea += sem * e * he;

        // coord MLP: tmp[t] = sum_h he[h]*W_c1[h][t]; he[h] broadcast via readlane
        float acc = bc1_t;
        for (int hh = 0; hh < H_; ++hh)
            acc += lane_bcast(he, hh) * wc1r[hh];
        const float sil = acc / (1.0f + __expf(-acc));
        const float cp  = sil * wc2_t;     // lane t's partial of coord(i,j)

        xa0 += d0*cp; xa1 += d1*cp; xa2 += d2c*cp;
        db0 += d0; db1 += d1; db2 += d2c;
    }

    // reduce xa over 64 lanes: sum_t (sum_j d_c*cp_t) = sum_j d_c*(coord - bc2)
    for (int m = 32; m >= 1; m >>= 1) {
        xa0 += __shfl_xor(xa0, m, 64);
        xa1 += __shfl_xor(xa1, m, 64);
        xa2 += __shfl_xor(xa2, m, 64);
    }

    const float attn = sqrtf(att0*att0 + att1*att1 + att2*att2 + EPS_);

    __shared__ float s_concat[F_+H_+K_];
    s_concat[t]        = h[bi*F_ + t];
    s_concat[F_ + t]   = hea / sum_e;
    s_concat[2*F_ + t] = attn;
    __syncthreads();

    if (t < 3) {
        const float xa = (t==0) ? xa0 : ((t==1) ? xa1 : xa2);
        const float db = (t==0) ? db0 : ((t==1) ? db1 : db2);
        out[(size_t)BN_*H_ + bi*3 + t] = x[bi*3+t] + xa + bc2*db;   // x_new (fp32)
    }

    float acc = b_n[t];
    for (int m = 0; m < F_+H_+K_; ++m)
        acc += s_concat[m] * W_n[m*H_ + t];
    out[bi*H_ + t] = acc;                                           // h_new (fp32)
}

extern "C" void kernel_launch(void* const* d_in, const int* in_sizes, int n_in,
                              void* d_out, int out_size, void* d_ws, size_t ws_size,
                              hipStream_t stream) {
    (void)in_sizes; (void)n_in; (void)out_size; (void)ws_size;
    const float* h    = (const float*)d_in[0];
    const float* x    = (const float*)d_in[1];
    const float* W_ew = (const float*)d_in[2];
    const float* b_ew = (const float*)d_in[3];
    const float* W_sa = (const float*)d_in[4];
    const float* W_es = (const float*)d_in[5];
    const float* b_es = (const float*)d_in[6];
    const float* W_c1 = (const float*)d_in[7];
    const float* b_c1 = (const float*)d_in[8];
    const float* W_c2 = (const float*)d_in[9];
    const float* b_c2 = (const float*)d_in[10];
    const float* W_n  = (const float*)d_in[11];
    const float* b_n  = (const float*)d_in[12];
    float* out = (float*)d_out;
    float* ws  = (float*)d_ws;

    proj_kernel<<<dim3(BN_), dim3(64), 0, stream>>>(h, W_ew, W_sa, W_es, ws);
    main_kernel<<<dim3(BN_), dim3(64), 0, stream>>>(h, x, b_ew, b_es, W_es, W_c1,
                                                    b_c1, W_c2, b_c2, W_n, b_n, ws, out);
}

// Round 10
// 544.177 us; speedup vs baseline: 1.3402x; 1.3402x over previous
//
#include <hip/hip_runtime.h>
#include <hip/hip_bf16.h>

#define B_ 4
#define N_ 512
#define F_ 64
#define H_ 64
#define K_ 64
#define BN_ (B_*N_)
#define EPS_ 1e-14f

__device__ __forceinline__ float lane_bcast(float v, int lane) {
    return __int_as_float(__builtin_amdgcn_readlane(__float_as_int(v), lane));
}

__device__ __forceinline__ float fast_tanh(float x) {
    // tanh(x) = 1 - 2/(e^{2x}+1), clamp to avoid overflow (tanh saturates anyway)
    const float xc = fminf(fmaxf(x, -15.f), 15.f);
    const float t  = __expf(2.0f * xc);
    return 1.0f - 2.0f / (t + 1.0f);
}

__device__ __forceinline__ float fast_silu(float x) {
    return x / (1.0f + __expf(-x));
}

// ws (floats): PJ_EW[BN*64] | PI_EW[BN*64] | PJ_ES[BN*64] | PI_ES[BN*64] | PJ_SA[BN] | PI_SA[BN]
#define W_PJEW 0
#define W_PIEW (BN_*64)
#define W_PJES (2*BN_*64)
#define W_PIES (3*BN_*64)
#define W_PJSA (4*BN_*64)
#define W_PISA (4*BN_*64 + BN_)

__global__ __launch_bounds__(64) void proj_kernel(
    const float* __restrict__ h, const float* __restrict__ W_ew,
    const float* __restrict__ W_sa, const float* __restrict__ W_es,
    float* __restrict__ ws)
{
    const int node = blockIdx.x;      // b*N + n
    const int t = threadIdx.x;        // 0..63 = output channel
    __shared__ float sh[F_];
    sh[t] = h[node*F_ + t];
    __syncthreads();
    float a_jew=0.f, a_iew=0.f, a_jes=0.f, a_ies=0.f, a_jsa=0.f, a_isa=0.f;
    for (int f = 0; f < F_; ++f) {
        const float hv = sh[f];
        a_jew += hv * W_ew[f*K_ + t];          // h @ W_ew[:F]
        a_iew += hv * W_ew[(F_+f)*K_ + t];     // h @ W_ew[F:]
        a_jes += hv * W_es[(1+f)*H_ + t];      // h @ W_es[1:][:F]
        a_ies += hv * W_es[(1+F_+f)*H_ + t];   // h @ W_es[1:][F:]
        a_jsa += hv * W_sa[f];                 // h @ W_sa[:F]
        a_isa += hv * W_sa[F_+f];              // h @ W_sa[F:]
    }
    ws[W_PJEW + node*K_ + t] = a_jew;
    ws[W_PIEW + node*K_ + t] = a_iew;
    ws[W_PJES + node*H_ + t] = a_jes;
    ws[W_PIES + node*H_ + t] = a_ies;
    if (t == 0) { ws[W_PJSA + node] = a_jsa; ws[W_PISA + node] = a_isa; }
}

__global__ __launch_bounds__(64, 1) void main_kernel(
    const float* __restrict__ h, const float* __restrict__ x,
    const float* __restrict__ b_ew, const float* __restrict__ b_es,
    const float* __restrict__ W_es, const float* __restrict__ W_c1,
    const float* __restrict__ b_c1, const float* __restrict__ W_c2,
    const float* __restrict__ b_c2, const float* __restrict__ W_n,
    const float* __restrict__ b_n,
    const float* __restrict__ ws, float* __restrict__ out)
{
    const int bi = blockIdx.x;        // b*N + i
    const int b  = bi >> 9;
    const int t  = threadIdx.x;       // 0..63 = channel (k or h index)
    const int base = b * N_;

    // reference: pair(i,j) = pj[j] + pi[i]; pj = h@W[:F], pi = h@W[F:]
    const float pi_ew_t = ws[W_PIEW + bi*K_ + t] + b_ew[t];
    const float pi_es_t = ws[W_PIES + bi*H_ + t] + b_es[t];
    const float pisa    = ws[W_PISA + bi];
    const float xi0 = x[bi*3+0], xi1 = x[bi*3+1], xi2 = x[bi*3+2];
    const float wes0_t = W_es[t];     // row 0 of W_es (weight of `filtered`)
    const float wc2_t  = W_c2[t];
    const float bc1_t  = b_c1[t];
    const float bc2    = b_c2[0];

    // W_c1 column t, register-resident (launch_bounds(64,1) frees the VGPR budget)
    float wc1r[H_];
    #pragma unroll
    for (int hh = 0; hh < H_; ++hh) wc1r[hh] = W_c1[hh*H_ + t];

    float att0=0.f, att1=0.f, att2=0.f, hea=0.f, sum_e=0.f;
    float xa0=0.f, xa1=0.f, xa2=0.f;   // per-lane: sum_j d_c * cp_lane
    float db0=0.f, db1=0.f, db2=0.f;   // sum_j d_c (lane-uniform)

    float nxt_ew = ws[W_PJEW + (size_t)base*K_ + t];
    float nxt_es = ws[W_PJES + (size_t)base*H_ + t];

    for (int j = 0; j < N_; ++j) {
        const int gj = base + j;
        const float pj_ew = nxt_ew;
        const float pj_es = nxt_es;
        const int jn = (j + 1 < N_) ? (gj + 1) : gj;   // clamped prefetch
        nxt_ew = ws[W_PJEW + (size_t)jn*K_ + t];
        nxt_es = ws[W_PJES + (size_t)jn*H_ + t];

        const float d0  = x[gj*3+0] - xi0;
        const float d1  = x[gj*3+1] - xi1;
        const float d2c = x[gj*3+2] - xi2;
        const float d2s = fmaf(d0, d0, fmaf(d1, d1, d2c*d2c));
        const float nrm = sqrtf(d2s + EPS_);
        const float e   = __expf(nrm);          // softmax numerator over j
        sum_e += e;
        const float filt = 1.0f / (nrm + 0.1f);
        const float inv  = 1.0f / fmaf(nrm, nrm, EPS_);
        const float v0 = d0*inv, v1 = d1*inv, v2 = d2c*inv;

        const float ewt = fast_tanh(pj_ew + pi_ew_t);
        att0 = fmaf(ewt, v0, att0);
        att1 = fmaf(ewt, v1, att1);
        att2 = fmaf(ewt, v2, att2);

        const float pre = fmaf(filt, wes0_t, pj_es + pi_es_t);
        const float he  = fast_silu(pre);

        const float sv  = ws[W_PJSA + gj] + pisa;
        const float sem = (sv >= 0.f) ? sv : 0.01f*sv;   // leaky relu
        hea = fmaf(sem * e, he, hea);

        // coord MLP: tmp[t] = sum_h he[h]*W_c1[h][t]; he[h] broadcast via readlane
        float acc0 = bc1_t, acc1v = 0.f, acc2v = 0.f, acc3v = 0.f;
        #pragma unroll
        for (int hh = 0; hh < H_; hh += 4) {
            acc0  = fmaf(lane_bcast(he, hh+0), wc1r[hh+0], acc0);
            acc1v = fmaf(lane_bcast(he, hh+1), wc1r[hh+1], acc1v);
            acc2v = fmaf(lane_bcast(he, hh+2), wc1r[hh+2], acc2v);
            acc3v = fmaf(lane_bcast(he, hh+3), wc1r[hh+3], acc3v);
        }
        const float acc = (acc0 + acc1v) + (acc2v + acc3v);
        const float sil = fast_silu(acc);
        const float cp  = sil * wc2_t;     // lane t's partial of coord(i,j)

        xa0 = fmaf(d0,  cp, xa0);
        xa1 = fmaf(d1,  cp, xa1);
        xa2 = fmaf(d2c, cp, xa2);
        db0 += d0; db1 += d1; db2 += d2c;
    }

    // reduce xa over 64 lanes: sum_t (sum_j d_c*cp_t) = sum_j d_c*(coord - bc2)
    for (int m = 32; m >= 1; m >>= 1) {
        xa0 += __shfl_xor(xa0, m, 64);
        xa1 += __shfl_xor(xa1, m, 64);
        xa2 += __shfl_xor(xa2, m, 64);
    }

    const float attn = sqrtf(fmaf(att0,att0, fmaf(att1,att1, att2*att2)) + EPS_);

    __shared__ float s_concat[F_+H_+K_];
    s_concat[t]        = h[bi*F_ + t];
    s_concat[F_ + t]   = hea / sum_e;
    s_concat[2*F_ + t] = attn;
    __syncthreads();

    if (t < 3) {
        const float xa = (t==0) ? xa0 : ((t==1) ? xa1 : xa2);
        const float db = (t==0) ? db0 : ((t==1) ? db1 : db2);
        out[(size_t)BN_*H_ + bi*3 + t] = x[bi*3+t] + xa + bc2*db;   // x_new (fp32)
    }

    float acc = b_n[t];
    for (int m = 0; m < F_+H_+K_; ++m)
        acc = fmaf(s_concat[m], W_n[m*H_ + t], acc);
    out[bi*H_ + t] = acc;                                           // h_new (fp32)
}

extern "C" void kernel_launch(void* const* d_in, const int* in_sizes, int n_in,
                              void* d_out, int out_size, void* d_ws, size_t ws_size,
                              hipStream_t stream) {
    (void)in_sizes; (void)n_in; (void)out_size; (void)ws_size;
    const float* h    = (const float*)d_in[0];
    const float* x    = (const float*)d_in[1];
    const float* W_ew = (const float*)d_in[2];
    const float* b_ew = (const float*)d_in[3];
    const float* W_sa = (const float*)d_in[4];
    const float* W_es = (const float*)d_in[5];
    const float* b_es = (const float*)d_in[6];
    const float* W_c1 = (const float*)d_in[7];
    const float* b_c1 = (const float*)d_in[8];
    const float* W_c2 = (const float*)d_in[9];
    const float* b_c2 = (const float*)d_in[10];
    const float* W_n  = (const float*)d_in[11];
    const float* b_n  = (const float*)d_in[12];
    float* out = (float*)d_out;
    float* ws  = (float*)d_ws;

    proj_kernel<<<dim3(BN_), dim3(64), 0, stream>>>(h, W_ew, W_sa, W_es, ws);
    main_kernel<<<dim3(BN_), dim3(64), 0, stream>>>(h, x, b_ew, b_es, W_es, W_c1,
                                                    b_c1, W_c2, b_c2, W_n, b_n, ws, out);
}

// Round 11
// 224.191 us; speedup vs baseline: 3.2530x; 2.4273x over previous
//
#include <hip/hip_runtime.h>

#define B_ 4
#define N_ 512
#define F_ 64
#define H_ 64
#define K_ 64
#define BN_ (B_*N_)
#define EPS_ 1e-14f

typedef __attribute__((ext_vector_type(8))) short short8;
typedef __attribute__((ext_vector_type(4))) float f32x4;

__device__ __forceinline__ unsigned short f2bf(float f) {
    const unsigned u = __float_as_uint(f);
    return (unsigned short)((u + 0x7FFFu + ((u >> 16) & 1u)) >> 16);
}
__device__ __forceinline__ float fast_tanh(float x) {
    const float xc = fminf(fmaxf(x, -15.f), 15.f);
    const float t  = __expf(2.0f * xc);
    return 1.0f - 2.0f / (t + 1.0f);
}
__device__ __forceinline__ float fast_silu(float x) {
    return x / (1.0f + __expf(-x));
}

// ws (floats): PJ_EW[BN*64] | PI_EW[BN*64] | PJ_ES[BN*64] | PI_ES[BN*64] | PJ_SA[BN] | PI_SA[BN]
#define W_PJEW 0
#define W_PIEW (BN_*64)
#define W_PJES (2*BN_*64)
#define W_PIES (3*BN_*64)
#define W_PJSA (4*BN_*64)
#define W_PISA (4*BN_*64 + BN_)

__global__ __launch_bounds__(64) void proj_kernel(
    const float* __restrict__ h, const float* __restrict__ W_ew,
    const float* __restrict__ W_sa, const float* __restrict__ W_es,
    float* __restrict__ ws)
{
    const int node = blockIdx.x;
    const int t = threadIdx.x;
    __shared__ float sh[F_];
    sh[t] = h[node*F_ + t];
    __syncthreads();
    float a_jew=0.f, a_iew=0.f, a_jes=0.f, a_ies=0.f, a_jsa=0.f, a_isa=0.f;
    for (int f = 0; f < F_; ++f) {
        const float hv = sh[f];
        a_jew += hv * W_ew[f*K_ + t];          // h @ W_ew[:F]
        a_iew += hv * W_ew[(F_+f)*K_ + t];     // h @ W_ew[F:]
        a_jes += hv * W_es[(1+f)*H_ + t];      // h @ W_es[1:][:F]
        a_ies += hv * W_es[(1+F_+f)*H_ + t];   // h @ W_es[1:][F:]
        a_jsa += hv * W_sa[f];
        a_isa += hv * W_sa[F_+f];
    }
    ws[W_PJEW + node*K_ + t] = a_jew;
    ws[W_PIEW + node*K_ + t] = a_iew;
    ws[W_PJES + node*H_ + t] = a_jes;
    ws[W_PIES + node*H_ + t] = a_ies;
    if (t == 0) { ws[W_PJSA + node] = a_jsa; ws[W_PISA + node] = a_isa; }
}

__global__ __launch_bounds__(256, 2) void main_kernel(
    const float* __restrict__ h, const float* __restrict__ x,
    const float* __restrict__ b_ew, const float* __restrict__ b_es,
    const float* __restrict__ W_es, const float* __restrict__ W_c1,
    const float* __restrict__ b_c1, const float* __restrict__ W_c2,
    const float* __restrict__ b_c2, const float* __restrict__ W_n,
    const float* __restrict__ b_n,
    const float* __restrict__ ws, float* __restrict__ out)
{
    const int bi   = blockIdx.x;          // b*N + i
    const int b    = bi >> 9;
    const int base = b * N_;
    const int tid  = threadIdx.x;
    const int w    = tid >> 6;            // wave 0..3
    const int lane = tid & 63;
    const int quad = lane >> 4;
    const int l16  = lane & 15;

    __shared__ unsigned short he_buf[4][64][72];  // bf16 he tiles, padded stride
    __shared__ float sdA[4][64][4];       // {v0,v1,v2,filt}
    __shared__ float sdB[4][64][4];       // {e*sem, d0,d1,d2}
    __shared__ float coord_buf[4][64];
    __shared__ float s_att[3][4][64];
    __shared__ float s_hea[4][64];
    __shared__ float s_misc[4][4];        // per wave: sum_e, xa0, xa1, xa2
    __shared__ float s_concat[192];

    // per-lane row-i constants (lane = channel t)
    const float pi_ew_t = ws[W_PIEW + bi*K_ + lane] + b_ew[lane];
    const float pi_es_t = ws[W_PIES + bi*H_ + lane] + b_es[lane];
    const float pisa    = ws[W_PISA + bi];
    const float xi0 = x[bi*3+0], xi1 = x[bi*3+1], xi2 = x[bi*3+2];
    const float wes0_t = W_es[lane];
    const float bc2    = b_c2[0];

    // epilogue constants per N-tile (col = nt*16 + l16)
    float bc1v[4], wc2v[4];
    #pragma unroll
    for (int nt = 0; nt < 4; ++nt) {
        bc1v[nt] = b_c1[nt*16 + l16];
        wc2v[nt] = W_c2[nt*16 + l16];
    }

    // W_c1 B-fragments (bf16), register-resident: B[k = kc*32+quad*8+r][n = nt*16+l16]
    short8 Bf[4][2];
    #pragma unroll
    for (int nt = 0; nt < 4; ++nt)
        #pragma unroll
        for (int kc = 0; kc < 2; ++kc)
            #pragma unroll
            for (int r = 0; r < 8; ++r) {
                const int k = kc*32 + quad*8 + r;
                Bf[nt][kc][r] = (short)f2bf(W_c1[k*H_ + nt*16 + l16]);
            }

    float att0=0.f, att1=0.f, att2=0.f, hea=0.f, sume=0.f;
    float xa0=0.f, xa1=0.f, xa2=0.f;

    for (int c = 0; c < 2; ++c) {
        const int j0 = (w*2 + c) * 64;

        // ---- phase A: per-j scalars (lane = jj) ----
        {
            const int gj = base + j0 + lane;
            const float d0 = x[gj*3+0] - xi0;
            const float d1 = x[gj*3+1] - xi1;
            const float d2 = x[gj*3+2] - xi2;
            const float d2s = fmaf(d0,d0, fmaf(d1,d1, d2*d2));
            const float nrm = sqrtf(d2s + EPS_);
            const float e   = __expf(nrm);
            sume += e;
            const float filt = 1.0f/(nrm + 0.1f);
            const float inv  = 1.0f/fmaf(nrm, nrm, EPS_);
            const float sv   = ws[W_PJSA + gj] + pisa;
            const float sem  = (sv >= 0.f) ? sv : 0.01f*sv;
            f32x4 p0 = { d0*inv, d1*inv, d2*inv, filt };
            f32x4 p1 = { e*sem, d0, d1, d2 };
            *(f32x4*)&sdA[w][lane][0] = p0;
            *(f32x4*)&sdB[w][lane][0] = p1;
        }
        __syncthreads();

        // ---- phase B: he + tanh/att (lane = channel t, loop over j) ----
        for (int jj = 0; jj < 64; ++jj) {
            const int gj = base + j0 + jj;
            const f32x4 p0 = *(const f32x4*)&sdA[w][jj][0];   // broadcast
            const float esem = sdB[w][jj][0];
            const float pj_es = ws[W_PJES + (size_t)gj*H_ + lane];
            const float pre = fmaf(p0.w, wes0_t, pj_es + pi_es_t);
            const float he  = fast_silu(pre);
            hea = fmaf(esem, he, hea);
            he_buf[w][jj][lane] = f2bf(he);
            const float pj_ew = ws[W_PJEW + (size_t)gj*K_ + lane];
            const float ewt = fast_tanh(pj_ew + pi_ew_t);
            att0 = fmaf(ewt, p0.x, att0);
            att1 = fmaf(ewt, p0.y, att1);
            att2 = fmaf(ewt, p0.z, att2);
        }
        __syncthreads();

        // ---- phase C: coord MLP via MFMA ----
        #pragma unroll
        for (int mt = 0; mt < 4; ++mt) {
            const short8 a0 = *(const short8*)&he_buf[w][mt*16 + l16][quad*8];
            const short8 a1 = *(const short8*)&he_buf[w][mt*16 + l16][32 + quad*8];
            float rs0=0.f, rs1=0.f, rs2=0.f, rs3=0.f;
            #pragma unroll
            for (int nt = 0; nt < 4; ++nt) {
                f32x4 acc = {0.f, 0.f, 0.f, 0.f};
                acc = __builtin_amdgcn_mfma_f32_16x16x32_bf16(a0, Bf[nt][0], acc, 0, 0, 0);
                acc = __builtin_amdgcn_mfma_f32_16x16x32_bf16(a1, Bf[nt][1], acc, 0, 0, 0);
                rs0 += fast_silu(acc[0] + bc1v[nt]) * wc2v[nt];
                rs1 += fast_silu(acc[1] + bc1v[nt]) * wc2v[nt];
                rs2 += fast_silu(acc[2] + bc1v[nt]) * wc2v[nt];
                rs3 += fast_silu(acc[3] + bc1v[nt]) * wc2v[nt];
            }
            #pragma unroll
            for (int m = 1; m <= 8; m <<= 1) {      // reduce over cols (l16)
                rs0 += __shfl_xor(rs0, m, 64);
                rs1 += __shfl_xor(rs1, m, 64);
                rs2 += __shfl_xor(rs2, m, 64);
                rs3 += __shfl_xor(rs3, m, 64);
            }
            if (l16 == 0) {
                f32x4 cv = { rs0 + bc2, rs1 + bc2, rs2 + bc2, rs3 + bc2 };
                *(f32x4*)&coord_buf[w][mt*16 + quad*4] = cv;   // rows quad*4+r
            }
        }
        __syncthreads();

        // ---- phase D: xa += d * coord (lane = jj) ----
        {
            const float cj = coord_buf[w][lane];
            const f32x4 p1 = *(const f32x4*)&sdB[w][lane][0];
            xa0 = fmaf(p1.y, cj, xa0);
            xa1 = fmaf(p1.z, cj, xa1);
            xa2 = fmaf(p1.w, cj, xa2);
        }
        __syncthreads();
    }

    // wave-level reduce of lane-partials (sum_e over j-lanes, xa over j-lanes)
    #pragma unroll
    for (int m = 32; m >= 1; m >>= 1) {
        sume += __shfl_xor(sume, m, 64);
        xa0  += __shfl_xor(xa0,  m, 64);
        xa1  += __shfl_xor(xa1,  m, 64);
        xa2  += __shfl_xor(xa2,  m, 64);
    }
    s_att[0][w][lane] = att0;
    s_att[1][w][lane] = att1;
    s_att[2][w][lane] = att2;
    s_hea[w][lane]    = hea;
    if (lane == 0) {
        s_misc[w][0] = sume; s_misc[w][1] = xa0; s_misc[w][2] = xa1; s_misc[w][3] = xa2;
    }
    __syncthreads();

    if (w == 0) {
        const float a0 = s_att[0][0][lane]+s_att[0][1][lane]+s_att[0][2][lane]+s_att[0][3][lane];
        const float a1 = s_att[1][0][lane]+s_att[1][1][lane]+s_att[1][2][lane]+s_att[1][3][lane];
        const float a2 = s_att[2][0][lane]+s_att[2][1][lane]+s_att[2][2][lane]+s_att[2][3][lane];
        const float hg = s_hea[0][lane]+s_hea[1][lane]+s_hea[2][lane]+s_hea[3][lane];
        const float se = s_misc[0][0]+s_misc[1][0]+s_misc[2][0]+s_misc[3][0];
        const float attn = sqrtf(fmaf(a0,a0, fmaf(a1,a1, a2*a2)) + EPS_);
        s_concat[lane]       = h[bi*F_ + lane];
        s_concat[64 + lane]  = hg / se;
        s_concat[128 + lane] = attn;
    }
    if (tid < 3) {
        const float xat = s_misc[0][1+tid]+s_misc[1][1+tid]+s_misc[2][1+tid]+s_misc[3][1+tid];
        out[(size_t)BN_*H_ + bi*3 + tid] = x[bi*3+tid] + xat;       // x_new
    }
    __syncthreads();
    if (w == 0) {
        float acc = b_n[lane];
        for (int m = 0; m < 192; ++m)
            acc = fmaf(s_concat[m], W_n[m*H_ + lane], acc);
        out[bi*H_ + lane] = acc;                                    // h_new
    }
}

extern "C" void kernel_launch(void* const* d_in, const int* in_sizes, int n_in,
                              void* d_out, int out_size, void* d_ws, size_t ws_size,
                              hipStream_t stream) {
    (void)in_sizes; (void)n_in; (void)out_size; (void)ws_size;
    const float* h    = (const float*)d_in[0];
    const float* x    = (const float*)d_in[1];
    const float* W_ew = (const float*)d_in[2];
    const float* b_ew = (const float*)d_in[3];
    const float* W_sa = (const float*)d_in[4];
    const float* W_es = (const float*)d_in[5];
    const float* b_es = (const float*)d_in[6];
    const float* W_c1 = (const float*)d_in[7];
    const float* b_c1 = (const float*)d_in[8];
    const float* W_c2 = (const float*)d_in[9];
    const float* b_c2 = (const float*)d_in[10];
    const float* W_n  = (const float*)d_in[11];
    const float* b_n  = (const float*)d_in[12];
    float* out = (float*)d_out;
    float* ws  = (float*)d_ws;

    proj_kernel<<<dim3(BN_), dim3(64), 0, stream>>>(h, W_ew, W_sa, W_es, ws);
    main_kernel<<<dim3(BN_), dim3(256), 0, stream>>>(h, x, b_ew, b_es, W_es, W_c1,
                                                     b_c1, W_c2, b_c2, W_n, b_n, ws, out);
}

// Round 12
// 210.244 us; speedup vs baseline: 3.4687x; 1.0663x over previous
//
#include <hip/hip_runtime.h>

#define B_ 4
#define N_ 512
#define F_ 64
#define H_ 64
#define K_ 64
#define BN_ (B_*N_)
#define EPS_ 1e-14f

typedef __attribute__((ext_vector_type(8))) short short8;
typedef __attribute__((ext_vector_type(4))) float f32x4;
typedef __attribute__((ext_vector_type(2))) float f32x2;

__device__ __forceinline__ unsigned short f2bf(float f) {
    const unsigned u = __float_as_uint(f);
    return (unsigned short)((u + 0x7FFFu + ((u >> 16) & 1u)) >> 16);
}
__device__ __forceinline__ float lane_bcast(float v, int lane) {
    return __int_as_float(__builtin_amdgcn_readlane(__float_as_int(v), lane));
}
__device__ __forceinline__ float fast_tanh(float x) {
    const float xc = fminf(fmaxf(x, -15.f), 15.f);
    const float t  = __expf(2.0f * xc);
    return 1.0f - 2.0f / (t + 1.0f);
}
__device__ __forceinline__ float fast_silu(float x) {
    return x / (1.0f + __expf(-x));
}

// ws (floats): PJ2[BN][64][2] ({ew,es} interleaved) | PI_EW[BN*64] | PI_ES[BN*64] | PJSA[BN] | PISA[BN]
#define W_PJ2  0
#define W_PIEW (BN_*128)
#define W_PIES (BN_*128 + BN_*64)
#define W_PJSA (BN_*128 + 2*BN_*64)
#define W_PISA (BN_*128 + 2*BN_*64 + BN_)

__global__ __launch_bounds__(64) void proj_kernel(
    const float* __restrict__ h, const float* __restrict__ W_ew,
    const float* __restrict__ W_sa, const float* __restrict__ W_es,
    float* __restrict__ ws)
{
    const int node = blockIdx.x;
    const int t = threadIdx.x;
    __shared__ float sh[F_];
    sh[t] = h[node*F_ + t];
    __syncthreads();
    float a_jew=0.f, a_iew=0.f, a_jes=0.f, a_ies=0.f, a_jsa=0.f, a_isa=0.f;
    for (int f = 0; f < F_; ++f) {
        const float hv = sh[f];
        a_jew += hv * W_ew[f*K_ + t];          // h @ W_ew[:F]
        a_iew += hv * W_ew[(F_+f)*K_ + t];     // h @ W_ew[F:]
        a_jes += hv * W_es[(1+f)*H_ + t];      // h @ W_es[1:][:F]
        a_ies += hv * W_es[(1+F_+f)*H_ + t];   // h @ W_es[1:][F:]
        a_jsa += hv * W_sa[f];
        a_isa += hv * W_sa[F_+f];
    }
    ws[W_PJ2 + (size_t)node*128 + t*2 + 0] = a_jew;
    ws[W_PJ2 + (size_t)node*128 + t*2 + 1] = a_jes;
    ws[W_PIEW + node*K_ + t] = a_iew;
    ws[W_PIES + node*H_ + t] = a_ies;
    if (t == 0) { ws[W_PJSA + node] = a_jsa; ws[W_PISA + node] = a_isa; }
}

__global__ __launch_bounds__(256, 3) void main_kernel(
    const float* __restrict__ h, const float* __restrict__ x,
    const float* __restrict__ b_ew, const float* __restrict__ b_es,
    const float* __restrict__ W_es, const float* __restrict__ W_c1,
    const float* __restrict__ b_c1, const float* __restrict__ W_c2,
    const float* __restrict__ b_c2, const float* __restrict__ W_n,
    const float* __restrict__ b_n,
    const float* __restrict__ ws, float* __restrict__ out)
{
    const int bi   = blockIdx.x;          // b*N + i
    const int b    = bi >> 9;
    const int base = b * N_;
    const int tid  = threadIdx.x;
    const int w    = tid >> 6;            // wave 0..3
    const int lane = tid & 63;
    const int quad = lane >> 4;
    const int l16  = lane & 15;

    // per-wave buffers: NO intra-chunk barriers needed (intra-wave DS ordering)
    __shared__ unsigned short he_buf[4][64][72];  // bf16 he, stride 72 (16B-aligned rows, 2-way banks)
    __shared__ float sdA[4][64][4];       // {v0,v1,v2,filt} per j
    __shared__ float coord_buf[4][64];
    __shared__ float s_att[3][4][64];
    __shared__ float s_hea[4][64];
    __shared__ float s_misc[4][4];        // per wave: sum_e, xa0, xa1, xa2
    __shared__ float s_concat[192];

    // per-lane row-i constants (lane = channel t)
    const float pi_ew_t = ws[W_PIEW + bi*K_ + lane] + b_ew[lane];
    const float pi_es_t = ws[W_PIES + bi*H_ + lane] + b_es[lane];
    const float pisa    = ws[W_PISA + bi];
    const float xi0 = x[bi*3+0], xi1 = x[bi*3+1], xi2 = x[bi*3+2];
    const float wes0_t = W_es[lane];
    const float bc2    = b_c2[0];

    float bc1v[4], wc2v[4];
    #pragma unroll
    for (int nt = 0; nt < 4; ++nt) {
        bc1v[nt] = b_c1[nt*16 + l16];
        wc2v[nt] = W_c2[nt*16 + l16];
    }

    // W_c1 B-fragments (bf16), register-resident
    short8 Bf[4][2];
    #pragma unroll
    for (int nt = 0; nt < 4; ++nt)
        #pragma unroll
        for (int kc = 0; kc < 2; ++kc)
            #pragma unroll
            for (int r = 0; r < 8; ++r) {
                const int k = kc*32 + quad*8 + r;
                Bf[nt][kc][r] = (short)f2bf(W_c1[k*H_ + nt*16 + l16]);
            }

    float att0=0.f, att1=0.f, att2=0.f, hea=0.f, sume=0.f;
    float xa0=0.f, xa1=0.f, xa2=0.f;

    for (int c = 0; c < 2; ++c) {
        const int j0 = (w*2 + c) * 64;

        // ---- phase A: per-j scalars (lane = jj) ----
        float esem, d0, d1, d2;
        {
            const int gj = base + j0 + lane;
            d0 = x[gj*3+0] - xi0;
            d1 = x[gj*3+1] - xi1;
            d2 = x[gj*3+2] - xi2;
            const float d2s = fmaf(d0,d0, fmaf(d1,d1, d2*d2));
            const float nrm = sqrtf(d2s + EPS_);
            const float e   = __expf(nrm);
            sume += e;
            const float filt = 1.0f/(nrm + 0.1f);
            const float inv  = 1.0f/fmaf(nrm, nrm, EPS_);
            const float sv   = ws[W_PJSA + gj] + pisa;
            const float sem  = (sv >= 0.f) ? sv : 0.01f*sv;
            esem = e * sem;
            f32x4 p0 = { d0*inv, d1*inv, d2*inv, filt };
            *(f32x4*)&sdA[w][lane][0] = p0;
        }

        // ---- phase B: he + tanh/att (lane = channel t, loop over j) ----
        #pragma unroll 4
        for (int jj = 0; jj < 64; ++jj) {
            const int gj = base + j0 + jj;
            const f32x2 pj = *(const f32x2*)&ws[W_PJ2 + (size_t)gj*128 + lane*2];
            const f32x4 p0 = *(const f32x4*)&sdA[w][jj][0];   // broadcast
            const float esem_s = lane_bcast(esem, jj);
            const float pre = fmaf(p0.w, wes0_t, pj.y + pi_es_t);
            const float he  = fast_silu(pre);
            hea = fmaf(esem_s, he, hea);
            he_buf[w][jj][lane] = f2bf(he);
            const float ewt = fast_tanh(pj.x + pi_ew_t);
            att0 = fmaf(ewt, p0.x, att0);
            att1 = fmaf(ewt, p0.y, att1);
            att2 = fmaf(ewt, p0.z, att2);
        }

        // ---- phase C: coord MLP via MFMA (reads own wave's he_buf) ----
        #pragma unroll
        for (int mt = 0; mt < 4; ++mt) {
            const short8 a0 = *(const short8*)&he_buf[w][mt*16 + l16][quad*8];
            const short8 a1 = *(const short8*)&he_buf[w][mt*16 + l16][32 + quad*8];
            float rs0=0.f, rs1=0.f, rs2=0.f, rs3=0.f;
            #pragma unroll
            for (int nt = 0; nt < 4; ++nt) {
                f32x4 acc = {0.f, 0.f, 0.f, 0.f};
                acc = __builtin_amdgcn_mfma_f32_16x16x32_bf16(a0, Bf[nt][0], acc, 0, 0, 0);
                acc = __builtin_amdgcn_mfma_f32_16x16x32_bf16(a1, Bf[nt][1], acc, 0, 0, 0);
                rs0 += fast_silu(acc[0] + bc1v[nt]) * wc2v[nt];
                rs1 += fast_silu(acc[1] + bc1v[nt]) * wc2v[nt];
                rs2 += fast_silu(acc[2] + bc1v[nt]) * wc2v[nt];
                rs3 += fast_silu(acc[3] + bc1v[nt]) * wc2v[nt];
            }
            #pragma unroll
            for (int m = 1; m <= 8; m <<= 1) {      // reduce over cols (l16)
                rs0 += __shfl_xor(rs0, m, 64);
                rs1 += __shfl_xor(rs1, m, 64);
                rs2 += __shfl_xor(rs2, m, 64);
                rs3 += __shfl_xor(rs3, m, 64);
            }
            if (l16 == 0) {
                f32x4 cv = { rs0 + bc2, rs1 + bc2, rs2 + bc2, rs3 + bc2 };
                *(f32x4*)&coord_buf[w][mt*16 + quad*4] = cv;
            }
        }

        // ---- phase D: xa += d * coord (lane = jj; own-lane d from phase A) ----
        {
            const float cj = coord_buf[w][lane];
            xa0 = fmaf(d0, cj, xa0);
            xa1 = fmaf(d1, cj, xa1);
            xa2 = fmaf(d2, cj, xa2);
        }
    }

    // wave-level reduce of j-lane partials
    #pragma unroll
    for (int m = 32; m >= 1; m >>= 1) {
        sume += __shfl_xor(sume, m, 64);
        xa0  += __shfl_xor(xa0,  m, 64);
        xa1  += __shfl_xor(xa1,  m, 64);
        xa2  += __shfl_xor(xa2,  m, 64);
    }
    s_att[0][w][lane] = att0;
    s_att[1][w][lane] = att1;
    s_att[2][w][lane] = att2;
    s_hea[w][lane]    = hea;
    if (lane == 0) {
        s_misc[w][0] = sume; s_misc[w][1] = xa0; s_misc[w][2] = xa1; s_misc[w][3] = xa2;
    }
    __syncthreads();

    if (w == 0) {
        const float a0 = s_att[0][0][lane]+s_att[0][1][lane]+s_att[0][2][lane]+s_att[0][3][lane];
        const float a1 = s_att[1][0][lane]+s_att[1][1][lane]+s_att[1][2][lane]+s_att[1][3][lane];
        const float a2 = s_att[2][0][lane]+s_att[2][1][lane]+s_att[2][2][lane]+s_att[2][3][lane];
        const float hg = s_hea[0][lane]+s_hea[1][lane]+s_hea[2][lane]+s_hea[3][lane];
        const float se = s_misc[0][0]+s_misc[1][0]+s_misc[2][0]+s_misc[3][0];
        const float attn = sqrtf(fmaf(a0,a0, fmaf(a1,a1, a2*a2)) + EPS_);
        s_concat[lane]       = h[bi*F_ + lane];
        s_concat[64 + lane]  = hg / se;
        s_concat[128 + lane] = attn;
    }
    if (tid < 3) {
        const float xat = s_misc[0][1+tid]+s_misc[1][1+tid]+s_misc[2][1+tid]+s_misc[3][1+tid];
        out[(size_t)BN_*H_ + bi*3 + tid] = x[bi*3+tid] + xat;       // x_new
    }
    __syncthreads();
    if (w == 0) {
        float acc = b_n[lane];
        for (int m = 0; m < 192; ++m)
            acc = fmaf(s_concat[m], W_n[m*H_ + lane], acc);
        out[bi*H_ + lane] = acc;                                    // h_new
    }
}

extern "C" void kernel_launch(void* const* d_in, const int* in_sizes, int n_in,
                              void* d_out, int out_size, void* d_ws, size_t ws_size,
                              hipStream_t stream) {
    (void)in_sizes; (void)n_in; (void)out_size; (void)ws_size;
    const float* h    = (const float*)d_in[0];
    const float* x    = (const float*)d_in[1];
    const float* W_ew = (const float*)d_in[2];
    const float* b_ew = (const float*)d_in[3];
    const float* W_sa = (const float*)d_in[4];
    const float* W_es = (const float*)d_in[5];
    const float* b_es = (const float*)d_in[6];
    const float* W_c1 = (const float*)d_in[7];
    const float* b_c1 = (const float*)d_in[8];
    const float* W_c2 = (const float*)d_in[9];
    const float* b_c2 = (const float*)d_in[10];
    const float* W_n  = (const float*)d_in[11];
    const float* b_n  = (const float*)d_in[12];
    float* out = (float*)d_out;
    float* ws  = (float*)d_ws;

    proj_kernel<<<dim3(BN_), dim3(64), 0, stream>>>(h, W_ew, W_sa, W_es, ws);
    main_kernel<<<dim3(BN_), dim3(256), 0, stream>>>(h, x, b_ew, b_es, W_es, W_c1,
                                                     b_c1, W_c2, b_c2, W_n, b_n, ws, out);
}

// Round 13
// 162.081 us; speedup vs baseline: 4.4995x; 1.2972x over previous
//
#include <hip/hip_runtime.h>

#define B_ 4
#define N_ 512
#define F_ 64
#define H_ 64
#define K_ 64
#define BN_ (B_*N_)
#define EPS_ 1e-14f

typedef __attribute__((ext_vector_type(8))) short short8;
typedef __attribute__((ext_vector_type(4))) float f32x4;
typedef __attribute__((ext_vector_type(2))) float f32x2;

__device__ __forceinline__ unsigned short f2bf(float f) {
    const unsigned u = __float_as_uint(f);
    return (unsigned short)((u + 0x7FFFu + ((u >> 16) & 1u)) >> 16);
}
__device__ __forceinline__ float lane_bcast(float v, int lane) {
    return __int_as_float(__builtin_amdgcn_readlane(__float_as_int(v), lane));
}
__device__ __forceinline__ float rcpf(float x) { return __builtin_amdgcn_rcpf(x); }
__device__ __forceinline__ float fast_tanh(float x) {
    // 1 - 2/(e^{2x}+1); no clamp needed: exp->inf => rcp->0 => 1, exp->0 => -1
    const float t = __expf(2.0f * x);
    return fmaf(-2.0f, rcpf(t + 1.0f), 1.0f);
}
__device__ __forceinline__ float fast_silu(float x) {
    return x * rcpf(1.0f + __expf(-x));
}

// ws (floats): PJ2[BN][64][2] ({ew,es} interleaved) | PI_EW[BN*64] | PI_ES[BN*64] | PJSA[BN] | PISA[BN]
#define W_PJ2  0
#define W_PIEW (BN_*128)
#define W_PIES (BN_*128 + BN_*64)
#define W_PJSA (BN_*128 + 2*BN_*64)
#define W_PISA (BN_*128 + 2*BN_*64 + BN_)

__global__ __launch_bounds__(64) void proj_kernel(
    const float* __restrict__ h, const float* __restrict__ W_ew,
    const float* __restrict__ W_sa, const float* __restrict__ W_es,
    float* __restrict__ ws)
{
    const int node = blockIdx.x;
    const int t = threadIdx.x;
    __shared__ float sh[F_];
    sh[t] = h[node*F_ + t];
    __syncthreads();
    float a_jew=0.f, a_iew=0.f, a_jes=0.f, a_ies=0.f, a_jsa=0.f, a_isa=0.f;
    #pragma unroll 8
    for (int f = 0; f < F_; ++f) {
        const float hv = sh[f];
        a_jew += hv * W_ew[f*K_ + t];          // h @ W_ew[:F]
        a_iew += hv * W_ew[(F_+f)*K_ + t];     // h @ W_ew[F:]
        a_jes += hv * W_es[(1+f)*H_ + t];      // h @ W_es[1:][:F]
        a_ies += hv * W_es[(1+F_+f)*H_ + t];   // h @ W_es[1:][F:]
        a_jsa += hv * W_sa[f];
        a_isa += hv * W_sa[F_+f];
    }
    ws[W_PJ2 + (size_t)node*128 + t*2 + 0] = a_jew;
    ws[W_PJ2 + (size_t)node*128 + t*2 + 1] = a_jes;
    ws[W_PIEW + node*K_ + t] = a_iew;
    ws[W_PIES + node*H_ + t] = a_ies;
    if (t == 0) { ws[W_PJSA + node] = a_jsa; ws[W_PISA + node] = a_isa; }
}

__global__ __launch_bounds__(256, 4) void main_kernel(
    const float* __restrict__ h, const float* __restrict__ x,
    const float* __restrict__ b_ew, const float* __restrict__ b_es,
    const float* __restrict__ W_es, const float* __restrict__ W_c1,
    const float* __restrict__ b_c1, const float* __restrict__ W_c2,
    const float* __restrict__ b_c2, const float* __restrict__ W_n,
    const float* __restrict__ b_n,
    const float* __restrict__ ws, float* __restrict__ out)
{
    const int bi   = blockIdx.x;          // b*N + i
    const int b    = bi >> 9;
    const int base = b * N_;
    const int tid  = threadIdx.x;
    const int w    = tid >> 6;            // wave 0..3
    const int lane = tid & 63;
    const int quad = lane >> 4;
    const int l16  = lane & 15;

    // per-wave buffers; intra-wave LDS ordering needs no block barriers
    __shared__ unsigned short he_buf[4][32][72];  // bf16 he subtile (32 j rows)
    __shared__ float sdA[4][64][4];       // {v0,v1,v2,filt} per j
    __shared__ float coord_buf[4][64];
    __shared__ float s_att[3][4][64];
    __shared__ float s_hea[4][64];
    __shared__ float s_misc[4][4];        // per wave: sum_e, xa0, xa1, xa2
    __shared__ float s_concat[192];
    __shared__ float s_hnew[4][64];

    const float pi_ew_t = ws[W_PIEW + bi*K_ + lane] + b_ew[lane];
    const float pi_es_t = ws[W_PIES + bi*H_ + lane] + b_es[lane];
    const float pisa    = ws[W_PISA + bi];
    const float xi0 = x[bi*3+0], xi1 = x[bi*3+1], xi2 = x[bi*3+2];
    const float wes0_t = W_es[lane];
    const float bc2    = b_c2[0];

    float bc1v[4], wc2v[4];
    #pragma unroll
    for (int nt = 0; nt < 4; ++nt) {
        bc1v[nt] = b_c1[nt*16 + l16];
        wc2v[nt] = W_c2[nt*16 + l16];
    }

    // W_c1 B-fragments (bf16), register-resident
    short8 Bf[4][2];
    #pragma unroll
    for (int nt = 0; nt < 4; ++nt)
        #pragma unroll
        for (int kc = 0; kc < 2; ++kc)
            #pragma unroll
            for (int r = 0; r < 8; ++r) {
                const int k = kc*32 + quad*8 + r;
                Bf[nt][kc][r] = (short)f2bf(W_c1[k*H_ + nt*16 + l16]);
            }

    float att0=0.f, att1=0.f, att2=0.f, hea=0.f, sume=0.f;
    float xa0=0.f, xa1=0.f, xa2=0.f;

    for (int c = 0; c < 2; ++c) {
        const int j0 = (w*2 + c) * 64;

        // ---- phase A: per-j scalars (lane = jj over 64) ----
        float esem, d0, d1, d2;
        {
            const int gj = base + j0 + lane;
            d0 = x[gj*3+0] - xi0;
            d1 = x[gj*3+1] - xi1;
            d2 = x[gj*3+2] - xi2;
            const float d2s = fmaf(d0,d0, fmaf(d1,d1, d2*d2));
            const float nrm = sqrtf(d2s + EPS_);
            const float e   = __expf(nrm);
            sume += e;
            const float filt = rcpf(nrm + 0.1f);
            const float inv  = rcpf(fmaf(nrm, nrm, EPS_));
            const float sv   = ws[W_PJSA + gj] + pisa;
            const float sem  = (sv >= 0.f) ? sv : 0.01f*sv;
            esem = e * sem;
            f32x4 p0 = { d0*inv, d1*inv, d2*inv, filt };
            *(f32x4*)&sdA[w][lane][0] = p0;
        }

        // two 32-j subchunks: phase B fills he subtile, phase C MFMAs it
        #pragma unroll
        for (int s = 0; s < 2; ++s) {
            const int sj = s*32;
            #pragma unroll 4
            for (int jj = 0; jj < 32; ++jj) {
                const int gj = base + j0 + sj + jj;
                const f32x2 pj = *(const f32x2*)&ws[W_PJ2 + (size_t)gj*128 + lane*2];
                const f32x4 p0 = *(const f32x4*)&sdA[w][sj + jj][0];   // broadcast
                const float esem_s = lane_bcast(esem, sj + jj);
                const float pre = fmaf(p0.w, wes0_t, pj.y + pi_es_t);
                const float he  = fast_silu(pre);
                hea = fmaf(esem_s, he, hea);
                he_buf[w][jj][lane] = f2bf(he);
                const float ewt = fast_tanh(pj.x + pi_ew_t);
                att0 = fmaf(ewt, p0.x, att0);
                att1 = fmaf(ewt, p0.y, att1);
                att2 = fmaf(ewt, p0.z, att2);
            }

            // ---- phase C: coord MLP via MFMA on the 32-row subtile ----
            #pragma unroll
            for (int mt = 0; mt < 2; ++mt) {
                const short8 a0 = *(const short8*)&he_buf[w][mt*16 + l16][quad*8];
                const short8 a1 = *(const short8*)&he_buf[w][mt*16 + l16][32 + quad*8];
                float rs0=0.f, rs1=0.f, rs2=0.f, rs3=0.f;
                #pragma unroll
                for (int nt = 0; nt < 4; ++nt) {
                    f32x4 acc = {0.f, 0.f, 0.f, 0.f};
                    acc = __builtin_amdgcn_mfma_f32_16x16x32_bf16(a0, Bf[nt][0], acc, 0, 0, 0);
                    acc = __builtin_amdgcn_mfma_f32_16x16x32_bf16(a1, Bf[nt][1], acc, 0, 0, 0);
                    rs0 += fast_silu(acc[0] + bc1v[nt]) * wc2v[nt];
                    rs1 += fast_silu(acc[1] + bc1v[nt]) * wc2v[nt];
                    rs2 += fast_silu(acc[2] + bc1v[nt]) * wc2v[nt];
                    rs3 += fast_silu(acc[3] + bc1v[nt]) * wc2v[nt];
                }
                #pragma unroll
                for (int m = 1; m <= 8; m <<= 1) {      // reduce over cols (l16)
                    rs0 += __shfl_xor(rs0, m, 64);
                    rs1 += __shfl_xor(rs1, m, 64);
                    rs2 += __shfl_xor(rs2, m, 64);
                    rs3 += __shfl_xor(rs3, m, 64);
                }
                if (l16 == 0) {
                    f32x4 cv = { rs0 + bc2, rs1 + bc2, rs2 + bc2, rs3 + bc2 };
                    *(f32x4*)&coord_buf[w][sj + mt*16 + quad*4] = cv;
                }
            }
        }

        // ---- phase D: xa += d * coord (lane = jj over 64) ----
        {
            const float cj = coord_buf[w][lane];
            xa0 = fmaf(d0, cj, xa0);
            xa1 = fmaf(d1, cj, xa1);
            xa2 = fmaf(d2, cj, xa2);
        }
    }

    // wave-level reduce of j-lane partials
    #pragma unroll
    for (int m = 32; m >= 1; m >>= 1) {
        sume += __shfl_xor(sume, m, 64);
        xa0  += __shfl_xor(xa0,  m, 64);
        xa1  += __shfl_xor(xa1,  m, 64);
        xa2  += __shfl_xor(xa2,  m, 64);
    }
    s_att[0][w][lane] = att0;
    s_att[1][w][lane] = att1;
    s_att[2][w][lane] = att2;
    s_hea[w][lane]    = hea;
    if (lane == 0) {
        s_misc[w][0] = sume; s_misc[w][1] = xa0; s_misc[w][2] = xa1; s_misc[w][3] = xa2;
    }
    __syncthreads();

    if (w == 0) {
        const float a0 = s_att[0][0][lane]+s_att[0][1][lane]+s_att[0][2][lane]+s_att[0][3][lane];
        const float a1 = s_att[1][0][lane]+s_att[1][1][lane]+s_att[1][2][lane]+s_att[1][3][lane];
        const float a2 = s_att[2][0][lane]+s_att[2][1][lane]+s_att[2][2][lane]+s_att[2][3][lane];
        const float hg = s_hea[0][lane]+s_hea[1][lane]+s_hea[2][lane]+s_hea[3][lane];
        const float se = s_misc[0][0]+s_misc[1][0]+s_misc[2][0]+s_misc[3][0];
        const float attn = sqrtf(fmaf(a0,a0, fmaf(a1,a1, a2*a2)) + EPS_);
        s_concat[lane]       = h[bi*F_ + lane];
        s_concat[64 + lane]  = hg * rcpf(se);
        s_concat[128 + lane] = attn;
    }
    if (tid < 3) {
        const float xat = s_misc[0][1+tid]+s_misc[1][1+tid]+s_misc[2][1+tid]+s_misc[3][1+tid];
        out[(size_t)BN_*H_ + bi*3 + tid] = x[bi*3+tid] + xat;       // x_new
    }
    __syncthreads();

    // output GEMV split across 4 waves (48 rows each)
    {
        float acc = 0.f;
        const int m0 = w * 48;
        #pragma unroll 8
        for (int m = m0; m < m0 + 48; ++m)
            acc = fmaf(s_concat[m], W_n[m*H_ + lane], acc);
        s_hnew[w][lane] = acc;
    }
    __syncthreads();
    if (w == 0) {
        out[bi*H_ + lane] = s_hnew[0][lane] + s_hnew[1][lane]
                          + s_hnew[2][lane] + s_hnew[3][lane] + b_n[lane];  // h_new
    }
}

extern "C" void kernel_launch(void* const* d_in, const int* in_sizes, int n_in,
                              void* d_out, int out_size, void* d_ws, size_t ws_size,
                              hipStream_t stream) {
    (void)in_sizes; (void)n_in; (void)out_size; (void)ws_size;
    const float* h    = (const float*)d_in[0];
    const float* x    = (const float*)d_in[1];
    const float* W_ew = (const float*)d_in[2];
    const float* b_ew = (const float*)d_in[3];
    const float* W_sa = (const float*)d_in[4];
    const float* W_es = (const float*)d_in[5];
    const float* b_es = (const float*)d_in[6];
    const float* W_c1 = (const float*)d_in[7];
    const float* b_c1 = (const float*)d_in[8];
    const float* W_c2 = (const float*)d_in[9];
    const float* b_c2 = (const float*)d_in[10];
    const float* W_n  = (const float*)d_in[11];
    const float* b_n  = (const float*)d_in[12];
    float* out = (float*)d_out;
    float* ws  = (float*)d_ws;

    proj_kernel<<<dim3(BN_), dim3(64), 0, stream>>>(h, W_ew, W_sa, W_es, ws);
    main_kernel<<<dim3(BN_), dim3(256), 0, stream>>>(h, x, b_ew, b_es, W_es, W_c1,
                                                     b_c1, W_c2, b_c2, W_n, b_n, ws, out);
}